// Round 1
// baseline (1003.189 us; speedup 1.0000x reference)
//
#include <hip/hip_runtime.h>

#define B_   2
#define T_   2048
#define C_   768
#define H_   12
#define HD_  64
#define M_   (B_ * T_)    // 4096 rows
#define N3_  (3 * C_)     // 2304

typedef __bf16 bf16_t;
typedef bf16_t bf16x8 __attribute__((ext_vector_type(8)));
typedef float  floatx4 __attribute__((ext_vector_type(4)));

__device__ inline floatx4 mfma_bf16(bf16x8 a, bf16x8 b, floatx4 c) {
    return __builtin_amdgcn_mfma_f32_16x16x32_bf16(a, b, c, 0, 0, 0);
}

// fp32 -> bf16 hi/lo split of 8 contiguous floats (for bf16x3 emulated-fp32 GEMM)
struct bf3 { bf16x8 hi; bf16x8 lo; };
__device__ inline bf3 load_split8(const float* __restrict__ p) {
    bf3 r;
#pragma unroll
    for (int j = 0; j < 8; ++j) {
        float f = p[j];
        bf16_t h = (bf16_t)f;
        r.hi[j] = h;
        r.lo[j] = (bf16_t)(f - (float)h);
    }
    return r;
}

// ---------------------------------------------------------------------------
// K1: qkv = x @ w_attn^T + b_attn   (bf16x3 for accuracy)
// wave-per-16x16-tile; epilogue scatters into q_f32, kw_f32 (=k*sel_w), and
// bf16 q/k/v for the attention kernels.
// ---------------------------------------------------------------------------
__global__ __launch_bounds__(256) void qkv_kernel(
    const float* __restrict__ x, const float* __restrict__ w,
    const float* __restrict__ bias, const float* __restrict__ selw,
    float* __restrict__ q_f, float* __restrict__ kw_f,
    bf16_t* __restrict__ q_b, bf16_t* __restrict__ k_b, bf16_t* __restrict__ v_b)
{
    int tid = threadIdx.x;
    int lane = tid & 63, wave = tid >> 6;
    int l15 = lane & 15, quad = lane >> 4;
    int m0 = blockIdx.x * 16;
    int n0 = blockIdx.y * 64 + wave * 16;
    const float* arow = x + (size_t)(m0 + l15) * C_ + quad * 8;
    const float* brow = w + (size_t)(n0 + l15) * C_ + quad * 8;
    floatx4 acc = {0.f, 0.f, 0.f, 0.f};
#pragma unroll 4
    for (int k0 = 0; k0 < C_; k0 += 32) {
        bf3 a  = load_split8(arow + k0);
        bf3 b8 = load_split8(brow + k0);
        acc = mfma_bf16(a.hi, b8.hi, acc);
        acc = mfma_bf16(a.hi, b8.lo, acc);
        acc = mfma_bf16(a.lo, b8.hi, acc);
    }
    int col = n0 + l15;
    float bb = bias[col];
#pragma unroll
    for (int r = 0; r < 4; ++r) {
        int row = m0 + quad * 4 + r;
        float v = acc[r] + bb;
        if (col < C_) {
            q_f[(size_t)row * C_ + col] = v;
            q_b[(size_t)row * C_ + col] = (bf16_t)v;
        } else if (col < 2 * C_) {
            int c2 = col - C_;
            k_b[(size_t)row * C_ + c2]  = (bf16_t)v;
            kw_f[(size_t)row * C_ + c2] = v * selw[c2 >> 6];  // per-head sel_w
        } else {
            int c2 = col - 2 * C_;
            v_b[(size_t)row * C_ + c2] = (bf16_t)v;
        }
    }
}

// ---------------------------------------------------------------------------
// K2: S[b,i,j] = (1<=j<i) ? relu(0.125 * q_i . kw_j) : 0     (bf16x3)
// Upper-triangle tiles just write zeros (scan needs fully-initialized buffer).
// ---------------------------------------------------------------------------
__global__ __launch_bounds__(256) void s_kernel(
    const float* __restrict__ q_f, const float* __restrict__ kw_f,
    float* __restrict__ SF)
{
    int tid = threadIdx.x;
    int lane = tid & 63, wave = tid >> 6;
    int l15 = lane & 15, quad = lane >> 4;
    int i0 = blockIdx.x * 16;
    int j0 = blockIdx.y * 64 + wave * 16;
    int b  = blockIdx.z;
    float* out = SF + (size_t)b * T_ * T_;
    if (j0 > i0) {  // tile fully masked (needs j < i)
#pragma unroll
        for (int r = 0; r < 4; ++r)
            out[(size_t)(i0 + quad * 4 + r) * T_ + (j0 + l15)] = 0.f;
        return;
    }
    const float* arow = q_f  + ((size_t)b * T_ + i0 + l15) * C_ + quad * 8;
    const float* brow = kw_f + ((size_t)b * T_ + j0 + l15) * C_ + quad * 8;
    floatx4 acc = {0.f, 0.f, 0.f, 0.f};
#pragma unroll 4
    for (int k0 = 0; k0 < C_; k0 += 32) {
        bf3 a  = load_split8(arow + k0);
        bf3 b8 = load_split8(brow + k0);
        acc = mfma_bf16(a.hi, b8.hi, acc);
        acc = mfma_bf16(a.hi, b8.lo, acc);
        acc = mfma_bf16(a.lo, b8.hi, acc);
    }
    int j = j0 + l15;
#pragma unroll
    for (int r = 0; r < 4; ++r) {
        int i = i0 + quad * 4 + r;
        float s = 0.125f * acc[r];
        s = (j >= 1 && j < i) ? fmaxf(s, 0.f) : 0.f;
        out[(size_t)i * T_ + j] = s;
    }
}

// ---------------------------------------------------------------------------
// K3-K5: per-column exclusive prefix sum over rows (FF_shifted), 3-phase scan.
// Segment layout: 16 segments x 128 rows. In-place: SF becomes FF_shifted.
// ---------------------------------------------------------------------------
#define SEG_    16
#define SEGLEN_ (T_ / SEG_)  // 128

__global__ __launch_bounds__(256) void scan_seg_sum(
    const float* __restrict__ SF, float* __restrict__ segsum)
{
    int gid  = blockIdx.x * 256 + threadIdx.x;      // B*SEG_*T_ threads
    int j    = gid & (T_ - 1);
    int rest = gid >> 11;
    int seg  = rest & (SEG_ - 1);
    int b    = rest >> 4;
    const float* col = SF + (size_t)b * T_ * T_ + (size_t)(seg * SEGLEN_) * T_ + j;
    float s = 0.f;
#pragma unroll 8
    for (int i = 0; i < SEGLEN_; ++i) s += col[(size_t)i * T_];
    segsum[((size_t)b * SEG_ + seg) * T_ + j] = s;
}

__global__ __launch_bounds__(256) void scan_seg_excl(float* __restrict__ segsum)
{
    int gid = blockIdx.x * 256 + threadIdx.x;       // B*T_ threads
    int j = gid & (T_ - 1);
    int b = gid >> 11;
    float run = 0.f;
#pragma unroll
    for (int s = 0; s < SEG_; ++s) {
        size_t idx = ((size_t)b * SEG_ + s) * T_ + j;
        float v = segsum[idx];
        segsum[idx] = run;
        run += v;
    }
}

__global__ __launch_bounds__(256) void scan_apply(
    float* __restrict__ SF, const float* __restrict__ segsum)
{
    int gid  = blockIdx.x * 256 + threadIdx.x;
    int j    = gid & (T_ - 1);
    int rest = gid >> 11;
    int seg  = rest & (SEG_ - 1);
    int b    = rest >> 4;
    float run = segsum[((size_t)b * SEG_ + seg) * T_ + j];
    float* col = SF + (size_t)b * T_ * T_ + (size_t)(seg * SEGLEN_) * T_ + j;
#pragma unroll 4
    for (int i = 0; i < SEGLEN_; ++i) {
        float s = col[(size_t)i * T_];
        col[(size_t)i * T_] = run;   // exclusive: FF_shifted[i,j]
        run += s;
    }
}

// ---------------------------------------------------------------------------
// K6: flash attention with FF offset.
// Block = (b, h, 64-row i-block), 4 waves, each wave a 16-row Q-tile.
// K-tile (32 rows) and V^T staged in LDS cooperatively; P goes C-layout ->
// LDS -> A-layout for PV. Online softmax state per row sits per (lane,reg)
// since C-layout row = quad*4+reg.
// ---------------------------------------------------------------------------
__global__ __launch_bounds__(256) void attn_kernel(
    const bf16_t* __restrict__ q_b, const bf16_t* __restrict__ k_b,
    const bf16_t* __restrict__ v_b, const float* __restrict__ FF,
    bf16_t* __restrict__ y_b)
{
    __shared__ __align__(16) bf16_t Ks[32][72];      // K rows, padded (144B = 9*16)
    __shared__ __align__(16) bf16_t VT[64][40];      // V^T, padded (80B = 5*16)
    __shared__ __align__(16) bf16_t Pb[4][16][40];   // per-wave P round-trip

    int tid = threadIdx.x;
    int lane = tid & 63, wave = tid >> 6;
    int l15 = lane & 15, quad = lane >> 4;
    int bi = blockIdx.x;
    int h = blockIdx.y, b = blockIdx.z;
    int i0 = bi * 64 + wave * 16;
    int imax = i0 + 15;
    int jmax_block = bi * 64 + 63;
    const float scale = 0.125f;

    const bf16_t* qrow = q_b + ((size_t)b * T_ + i0 + l15) * C_ + h * HD_;
    bf16x8 qa0 = *(const bf16x8*)(qrow + quad * 8);
    bf16x8 qa1 = *(const bf16x8*)(qrow + 32 + quad * 8);

    const floatx4 fzero = {0.f, 0.f, 0.f, 0.f};
    float m_run[4], l_run[4];
    floatx4 O[4];
#pragma unroll
    for (int r = 0; r < 4; ++r) { m_run[r] = -__builtin_inff(); l_run[r] = 0.f; }
#pragma unroll
    for (int nt = 0; nt < 4; ++nt) O[nt] = fzero;

    for (int j0 = 0; j0 <= jmax_block; j0 += 32) {
        __syncthreads();
        {   // cooperative stage: K rows straight, V transposed
            int rowj = tid >> 3, dch = tid & 7;
            const bf16_t* ksrc = k_b + ((size_t)b * T_ + j0 + rowj) * C_ + h * HD_ + dch * 8;
            *(int4*)(&Ks[rowj][dch * 8]) = *(const int4*)ksrc;
            const bf16_t* vsrc = v_b + ((size_t)b * T_ + j0 + rowj) * C_ + h * HD_ + dch * 8;
            union { int4 i4; bf16_t e[8]; } u;
            u.i4 = *(const int4*)vsrc;
#pragma unroll
            for (int t = 0; t < 8; ++t) VT[dch * 8 + t][rowj] = u.e[t];
        }
        __syncthreads();
        if (j0 > imax) continue;   // wave-uniform skip; barriers stay uniform

        // QK^T: P[16 x 32] = 2 n-subtiles x 2 k-chunks
        floatx4 pc[2];
#pragma unroll
        for (int s = 0; s < 2; ++s) {
            bf16x8 kb0 = *(const bf16x8*)(&Ks[s * 16 + l15][quad * 8]);
            bf16x8 kb1 = *(const bf16x8*)(&Ks[s * 16 + l15][32 + quad * 8]);
            floatx4 p = fzero;
            p = mfma_bf16(qa0, kb0, p);
            p = mfma_bf16(qa1, kb1, p);
            pc[s] = p;
        }
        // logits = scale*qk - FF, causal mask
        float lg[2][4];
#pragma unroll
        for (int s = 0; s < 2; ++s) {
            int j = j0 + s * 16 + l15;
#pragma unroll
            for (int r = 0; r < 4; ++r) {
                int i = i0 + quad * 4 + r;
                float ff = FF[((size_t)b * T_ + i) * T_ + j];
                lg[s][r] = (j <= i) ? pc[s][r] * scale - ff : -__builtin_inff();
            }
        }
        // online softmax per row (row = quad*4+r; 16 lanes of a quad share rows)
#pragma unroll
        for (int r = 0; r < 4; ++r) {
            float rm = fmaxf(lg[0][r], lg[1][r]);
#pragma unroll
            for (int d = 1; d < 16; d <<= 1) rm = fmaxf(rm, __shfl_xor(rm, d));
            float mn = fmaxf(m_run[r], rm);
            float alpha = __expf(m_run[r] - mn);
            float p0 = __expf(lg[0][r] - mn);
            float p1 = __expf(lg[1][r] - mn);
            lg[0][r] = p0; lg[1][r] = p1;
            float ps = p0 + p1;
#pragma unroll
            for (int d = 1; d < 16; d <<= 1) ps += __shfl_xor(ps, d);
            l_run[r] = l_run[r] * alpha + ps;
            m_run[r] = mn;
#pragma unroll
            for (int nt = 0; nt < 4; ++nt) O[nt][r] *= alpha;
        }
        // P: C-layout regs -> LDS -> A-layout frag (wave-local buffer)
#pragma unroll
        for (int s = 0; s < 2; ++s)
#pragma unroll
            for (int r = 0; r < 4; ++r)
                Pb[wave][quad * 4 + r][s * 16 + l15] = (bf16_t)lg[s][r];
        asm volatile("s_waitcnt lgkmcnt(0)" ::: "memory");
        bf16x8 pa = *(const bf16x8*)(&Pb[wave][l15][quad * 8]);
#pragma unroll
        for (int nt = 0; nt < 4; ++nt) {
            bf16x8 vb = *(const bf16x8*)(&VT[nt * 16 + l15][quad * 8]);
            O[nt] = mfma_bf16(pa, vb, O[nt]);
        }
    }
    // epilogue: normalize, write y (bf16, [b,t,h*64+d])
#pragma unroll
    for (int r = 0; r < 4; ++r) {
        float inv = 1.f / l_run[r];
        int i = i0 + quad * 4 + r;
#pragma unroll
        for (int nt = 0; nt < 4; ++nt)
            y_b[((size_t)b * T_ + i) * C_ + h * HD_ + nt * 16 + l15] =
                (bf16_t)(O[nt][r] * inv);
    }
}

// ---------------------------------------------------------------------------
// K7: out = y @ w_proj^T + b_proj  (plain bf16 MFMA; w converted on the fly)
// ---------------------------------------------------------------------------
__global__ __launch_bounds__(256) void proj_kernel(
    const bf16_t* __restrict__ y_b, const float* __restrict__ w,
    const float* __restrict__ bias, float* __restrict__ out)
{
    int tid = threadIdx.x;
    int lane = tid & 63, wave = tid >> 6;
    int l15 = lane & 15, quad = lane >> 4;
    int m0 = blockIdx.x * 16, n0 = blockIdx.y * 64 + wave * 16;
    const bf16_t* arow = y_b + (size_t)(m0 + l15) * C_ + quad * 8;
    const float*  brow = w   + (size_t)(n0 + l15) * C_ + quad * 8;
    floatx4 acc = {0.f, 0.f, 0.f, 0.f};
#pragma unroll 4
    for (int k0 = 0; k0 < C_; k0 += 32) {
        bf16x8 a = *(const bf16x8*)(arow + k0);
        bf16x8 b8;
#pragma unroll
        for (int jj = 0; jj < 8; ++jj) b8[jj] = (bf16_t)brow[k0 + jj];
        acc = mfma_bf16(a, b8, acc);
    }
    int col = n0 + l15;
    float bb = bias[col];
#pragma unroll
    for (int r = 0; r < 4; ++r)
        out[(size_t)(m0 + quad * 4 + r) * C_ + col] = acc[r] + bb;
}

// ---------------------------------------------------------------------------
extern "C" void kernel_launch(void* const* d_in, const int* in_sizes, int n_in,
                              void* d_out, int out_size, void* d_ws, size_t ws_size,
                              hipStream_t stream)
{
    const float* x      = (const float*)d_in[0];
    const float* w_attn = (const float*)d_in[1];
    const float* b_attn = (const float*)d_in[2];
    const float* w_proj = (const float*)d_in[3];
    const float* b_proj = (const float*)d_in[4];
    const float* sel_w  = (const float*)d_in[5];
    float* out = (float*)d_out;

    char* ws = (char*)d_ws;
    size_t off = 0;
    auto alloc = [&](size_t bytes) {
        void* p = ws + off;
        off += (bytes + 255) & ~(size_t)255;
        return p;
    };
    float*  q_f    = (float*)alloc((size_t)M_ * C_ * 4);
    float*  kw_f   = (float*)alloc((size_t)M_ * C_ * 4);
    float*  SF     = (float*)alloc((size_t)B_ * T_ * T_ * 4);
    float*  segsum = (float*)alloc((size_t)B_ * SEG_ * T_ * 4);
    bf16_t* q_b    = (bf16_t*)alloc((size_t)M_ * C_ * 2);
    bf16_t* k_b    = (bf16_t*)alloc((size_t)M_ * C_ * 2);
    bf16_t* v_b    = (bf16_t*)alloc((size_t)M_ * C_ * 2);
    bf16_t* y_b    = (bf16_t*)alloc((size_t)M_ * C_ * 2);

    qkv_kernel<<<dim3(M_ / 16, N3_ / 64), 256, 0, stream>>>(
        x, w_attn, b_attn, sel_w, q_f, kw_f, q_b, k_b, v_b);
    s_kernel<<<dim3(T_ / 16, T_ / 64, B_), 256, 0, stream>>>(q_f, kw_f, SF);
    scan_seg_sum<<<dim3(B_ * SEG_ * T_ / 256), 256, 0, stream>>>(SF, segsum);
    scan_seg_excl<<<dim3(B_ * T_ / 256), 256, 0, stream>>>(segsum);
    scan_apply<<<dim3(B_ * SEG_ * T_ / 256), 256, 0, stream>>>(SF, segsum);
    attn_kernel<<<dim3(T_ / 64, H_, B_), 256, 0, stream>>>(q_b, k_b, v_b, SF, y_b);
    proj_kernel<<<dim3(M_ / 16, C_ / 64), 256, 0, stream>>>(y_b, w_proj, b_proj, out);
}

// Round 2
// 449.686 us; speedup vs baseline: 2.2309x; 2.2309x over previous
//
#include <hip/hip_runtime.h>

#define B_   2
#define T_   2048
#define C_   768
#define H_   12
#define HD_  64
#define M_   (B_ * T_)    // 4096 rows
#define N3_  (3 * C_)     // 2304
#define KB_  (C_ * 2)     // 1536 bytes per row (bf16)

typedef __bf16 bf16_t;
typedef bf16_t bf16x8 __attribute__((ext_vector_type(8)));
typedef float  floatx4 __attribute__((ext_vector_type(4)));

__device__ inline floatx4 mfma_bf16(bf16x8 a, bf16x8 b, floatx4 c) {
    return __builtin_amdgcn_mfma_f32_16x16x32_bf16(a, b, c, 0, 0, 0);
}

__device__ __forceinline__ void async_copy16(const void* g, void* l) {
    __builtin_amdgcn_global_load_lds(
        (const __attribute__((address_space(1))) void*)g,
        (__attribute__((address_space(3))) void*)l, 16, 0, 0);
}

// ---------------------------------------------------------------------------
// Shared 128x128-tile GEMM mainloop. A,B row-major [rows][K] bf16, K=768.
// LDS per array: [128 rows][4 slots of 16B]; row r, k-group g stored at slot
// g ^ ((r>>1)&3)  -> 2-way bank aliasing only (free), staging stays
// lane-contiguous for global_load_lds (permutation within each 64B row).
// ---------------------------------------------------------------------------
__device__ __forceinline__ void stage8k(const char* tile, char* ldsbase,
                                        int k0b, int wave, int lane) {
#pragma unroll
    for (int i = 0; i < 2; ++i) {
        int p = (wave * 2 + i) * 64 + lane;     // 16B slot index 0..511
        int r = p >> 2, slot = p & 3;
        int g = slot ^ ((r >> 1) & 3);
        async_copy16(tile + (size_t)r * KB_ + k0b + g * 16, ldsbase + p * 16);
    }
}

__device__ __forceinline__ bf16x8 frag_read(const char* ldsbase, int row, int quad) {
    int slot = quad ^ ((row >> 1) & 3);
    return *(const bf16x8*)(ldsbase + row * 64 + slot * 16);
}

template<bool TRIPLE>
__device__ __forceinline__ void gemm_loop(
    const char* Ah, const char* Al, const char* Bh, const char* Bl,
    char* lds, floatx4 (&acc)[4][4])
{
    int tid = threadIdx.x, lane = tid & 63, wave = tid >> 6;
    int l15 = lane & 15, quad = lane >> 4;
    int wr = wave >> 1, wc = wave & 1;
    char* LAh = lds;
    char* LAl = lds + 8192;
    char* LBh = lds + (TRIPLE ? 16384 : 8192);
    char* LBl = lds + 24576;
#pragma unroll 1
    for (int k0 = 0; k0 < KB_; k0 += 64) {       // 32 bf16 per chunk
        __syncthreads();
        stage8k(Ah, LAh, k0, wave, lane);
        if (TRIPLE) stage8k(Al, LAl, k0, wave, lane);
        stage8k(Bh, LBh, k0, wave, lane);
        if (TRIPLE) stage8k(Bl, LBl, k0, wave, lane);
        __syncthreads();
        bf16x8 ah[4], al[4], bh[4], bl[4];
#pragma unroll
        for (int t = 0; t < 4; ++t) {
            ah[t] = frag_read(LAh, wr * 64 + t * 16 + l15, quad);
            bh[t] = frag_read(LBh, wc * 64 + t * 16 + l15, quad);
            if (TRIPLE) {
                al[t] = frag_read(LAl, wr * 64 + t * 16 + l15, quad);
                bl[t] = frag_read(LBl, wc * 64 + t * 16 + l15, quad);
            }
        }
#pragma unroll
        for (int mi = 0; mi < 4; ++mi)
#pragma unroll
            for (int ni = 0; ni < 4; ++ni) {
                acc[mi][ni] = mfma_bf16(ah[mi], bh[ni], acc[mi][ni]);
                if (TRIPLE) {
                    acc[mi][ni] = mfma_bf16(ah[mi], bl[ni], acc[mi][ni]);
                    acc[mi][ni] = mfma_bf16(al[mi], bh[ni], acc[mi][ni]);
                }
            }
    }
}

// ---------------------------------------------------------------------------
// K0: fp32 -> bf16 hi/lo split (and plain convert)
// ---------------------------------------------------------------------------
__global__ __launch_bounds__(256) void split_f32(
    const float* __restrict__ src, bf16_t* __restrict__ hi,
    bf16_t* __restrict__ lo, int n)
{
    int i = blockIdx.x * 256 + threadIdx.x;
    if (i < n) {
        float f = src[i];
        bf16_t h = (bf16_t)f;
        hi[i] = h;
        lo[i] = (bf16_t)(f - (float)h);
    }
}

__global__ __launch_bounds__(256) void conv_f32(
    const float* __restrict__ src, bf16_t* __restrict__ dst, int n)
{
    int i = blockIdx.x * 256 + threadIdx.x;
    if (i < n) dst[i] = (bf16_t)src[i];
}

// ---------------------------------------------------------------------------
// K1: qkv = x @ w_attn^T + b_attn  (bf16x3). Epilogue scatters into
// q hi/lo (q_hi doubles as attention's bf16 q), kw hi/lo (=k*sel_w), k_b, v_b.
// ---------------------------------------------------------------------------
__global__ __launch_bounds__(256) void qkv_gemm(
    const bf16_t* __restrict__ x_hi, const bf16_t* __restrict__ x_lo,
    const bf16_t* __restrict__ w_hi, const bf16_t* __restrict__ w_lo,
    const float* __restrict__ bias, const float* __restrict__ selw,
    bf16_t* __restrict__ q_hi, bf16_t* __restrict__ q_lo,
    bf16_t* __restrict__ kw_hi, bf16_t* __restrict__ kw_lo,
    bf16_t* __restrict__ k_b, bf16_t* __restrict__ v_b)
{
    extern __shared__ char lds[];
    int m0 = blockIdx.x * 128, n0 = blockIdx.y * 128;
    floatx4 acc[4][4];
#pragma unroll
    for (int i = 0; i < 4; ++i)
#pragma unroll
        for (int j = 0; j < 4; ++j) acc[i][j] = (floatx4){0.f, 0.f, 0.f, 0.f};
    gemm_loop<true>((const char*)(x_hi + (size_t)m0 * C_),
                    (const char*)(x_lo + (size_t)m0 * C_),
                    (const char*)(w_hi + (size_t)n0 * C_),
                    (const char*)(w_lo + (size_t)n0 * C_), lds, acc);

    int tid = threadIdx.x, lane = tid & 63, wave = tid >> 6;
    int l15 = lane & 15, quad = lane >> 4;
    int wr = wave >> 1, wc = wave & 1;
    int cb = n0 + wc * 64;   // wave-uniform: section (q/k/v) is uniform
#pragma unroll
    for (int ni = 0; ni < 4; ++ni) {
        int col = cb + ni * 16 + l15;
        float bb = bias[col];
#pragma unroll
        for (int mi = 0; mi < 4; ++mi)
#pragma unroll
            for (int r = 0; r < 4; ++r) {
                int row = m0 + wr * 64 + mi * 16 + quad * 4 + r;
                float v = acc[mi][ni][r] + bb;
                if (cb < C_) {
                    bf16_t h = (bf16_t)v;
                    q_hi[(size_t)row * C_ + col] = h;
                    q_lo[(size_t)row * C_ + col] = (bf16_t)(v - (float)h);
                } else if (cb < 2 * C_) {
                    int c2 = col - C_;
                    k_b[(size_t)row * C_ + c2] = (bf16_t)v;
                    float kw = v * selw[c2 >> 6];
                    bf16_t h = (bf16_t)kw;
                    kw_hi[(size_t)row * C_ + c2] = h;
                    kw_lo[(size_t)row * C_ + c2] = (bf16_t)(kw - (float)h);
                } else {
                    v_b[(size_t)row * C_ + (col - 2 * C_)] = (bf16_t)v;
                }
            }
    }
}

// ---------------------------------------------------------------------------
// K2: S[b,i,j] = (1<=j<i) ? relu(0.125 * q_i . kw_j) : 0   (bf16x3)
// ---------------------------------------------------------------------------
__global__ __launch_bounds__(256) void s_gemm(
    const bf16_t* __restrict__ q_hi, const bf16_t* __restrict__ q_lo,
    const bf16_t* __restrict__ kw_hi, const bf16_t* __restrict__ kw_lo,
    float* __restrict__ SF)
{
    extern __shared__ char lds[];
    int i0 = blockIdx.x * 128, j0 = blockIdx.y * 128, b = blockIdx.z;
    float* out = SF + (size_t)b * T_ * T_;
    int tid = threadIdx.x;
    if (j0 > i0) {   // fully-masked tile: zero-fill (scan needs init'd buffer)
        float4 z = {0.f, 0.f, 0.f, 0.f};
        float* p = out + (size_t)(i0 + (tid >> 1)) * T_ + j0 + (tid & 1) * 64;
#pragma unroll
        for (int c = 0; c < 16; ++c) ((float4*)p)[c] = z;
        return;
    }
    floatx4 acc[4][4];
#pragma unroll
    for (int i = 0; i < 4; ++i)
#pragma unroll
        for (int j = 0; j < 4; ++j) acc[i][j] = (floatx4){0.f, 0.f, 0.f, 0.f};
    size_t arow = ((size_t)b * T_ + i0) * C_;
    size_t brow = ((size_t)b * T_ + j0) * C_;
    gemm_loop<true>((const char*)(q_hi + arow), (const char*)(q_lo + arow),
                    (const char*)(kw_hi + brow), (const char*)(kw_lo + brow),
                    lds, acc);

    int lane = tid & 63, wave = tid >> 6;
    int l15 = lane & 15, quad = lane >> 4;
    int wr = wave >> 1, wc = wave & 1;
#pragma unroll
    for (int ni = 0; ni < 4; ++ni) {
        int j = j0 + wc * 64 + ni * 16 + l15;
#pragma unroll
        for (int mi = 0; mi < 4; ++mi)
#pragma unroll
            for (int r = 0; r < 4; ++r) {
                int i = i0 + wr * 64 + mi * 16 + quad * 4 + r;
                float s = 0.125f * acc[mi][ni][r];
                s = (j >= 1 && j < i) ? fmaxf(s, 0.f) : 0.f;
                out[(size_t)i * T_ + j] = s;
            }
    }
}

// ---------------------------------------------------------------------------
// K3-K5: per-column exclusive prefix sum over rows (FF_shifted), 3-phase.
// ---------------------------------------------------------------------------
#define SEG_    16
#define SEGLEN_ (T_ / SEG_)  // 128

__global__ __launch_bounds__(256) void scan_seg_sum(
    const float* __restrict__ SF, float* __restrict__ segsum)
{
    int gid  = blockIdx.x * 256 + threadIdx.x;
    int j    = gid & (T_ - 1);
    int rest = gid >> 11;
    int seg  = rest & (SEG_ - 1);
    int b    = rest >> 4;
    const float* col = SF + (size_t)b * T_ * T_ + (size_t)(seg * SEGLEN_) * T_ + j;
    float s = 0.f;
#pragma unroll 8
    for (int i = 0; i < SEGLEN_; ++i) s += col[(size_t)i * T_];
    segsum[((size_t)b * SEG_ + seg) * T_ + j] = s;
}

__global__ __launch_bounds__(256) void scan_seg_excl(float* __restrict__ segsum)
{
    int gid = blockIdx.x * 256 + threadIdx.x;
    int j = gid & (T_ - 1);
    int b = gid >> 11;
    float run = 0.f;
#pragma unroll
    for (int s = 0; s < SEG_; ++s) {
        size_t idx = ((size_t)b * SEG_ + s) * T_ + j;
        float v = segsum[idx];
        segsum[idx] = run;
        run += v;
    }
}

__global__ __launch_bounds__(256) void scan_apply(
    float* __restrict__ SF, const float* __restrict__ segsum)
{
    int gid  = blockIdx.x * 256 + threadIdx.x;
    int j    = gid & (T_ - 1);
    int rest = gid >> 11;
    int seg  = rest & (SEG_ - 1);
    int b    = rest >> 4;
    float run = segsum[((size_t)b * SEG_ + seg) * T_ + j];
    float* col = SF + (size_t)b * T_ * T_ + (size_t)(seg * SEGLEN_) * T_ + j;
#pragma unroll 4
    for (int i = 0; i < SEGLEN_; ++i) {
        float s = col[(size_t)i * T_];
        col[(size_t)i * T_] = run;   // exclusive: FF_shifted[i,j]
        run += s;
    }
}

// ---------------------------------------------------------------------------
// K6: flash attention with FF offset (unchanged from round 1 — correct).
// ---------------------------------------------------------------------------
__global__ __launch_bounds__(256) void attn_kernel(
    const bf16_t* __restrict__ q_b, const bf16_t* __restrict__ k_b,
    const bf16_t* __restrict__ v_b, const float* __restrict__ FF,
    bf16_t* __restrict__ y_b)
{
    __shared__ __align__(16) bf16_t Ks[32][72];
    __shared__ __align__(16) bf16_t VT[64][40];
    __shared__ __align__(16) bf16_t Pb[4][16][40];

    int tid = threadIdx.x;
    int lane = tid & 63, wave = tid >> 6;
    int l15 = lane & 15, quad = lane >> 4;
    int bi = blockIdx.x;
    int h = blockIdx.y, b = blockIdx.z;
    int i0 = bi * 64 + wave * 16;
    int imax = i0 + 15;
    int jmax_block = bi * 64 + 63;
    const float scale = 0.125f;

    const bf16_t* qrow = q_b + ((size_t)b * T_ + i0 + l15) * C_ + h * HD_;
    bf16x8 qa0 = *(const bf16x8*)(qrow + quad * 8);
    bf16x8 qa1 = *(const bf16x8*)(qrow + 32 + quad * 8);

    const floatx4 fzero = {0.f, 0.f, 0.f, 0.f};
    float m_run[4], l_run[4];
    floatx4 O[4];
#pragma unroll
    for (int r = 0; r < 4; ++r) { m_run[r] = -__builtin_inff(); l_run[r] = 0.f; }
#pragma unroll
    for (int nt = 0; nt < 4; ++nt) O[nt] = fzero;

    for (int j0 = 0; j0 <= jmax_block; j0 += 32) {
        __syncthreads();
        {
            int rowj = tid >> 3, dch = tid & 7;
            const bf16_t* ksrc = k_b + ((size_t)b * T_ + j0 + rowj) * C_ + h * HD_ + dch * 8;
            *(int4*)(&Ks[rowj][dch * 8]) = *(const int4*)ksrc;
            const bf16_t* vsrc = v_b + ((size_t)b * T_ + j0 + rowj) * C_ + h * HD_ + dch * 8;
            union { int4 i4; bf16_t e[8]; } u;
            u.i4 = *(const int4*)vsrc;
#pragma unroll
            for (int t = 0; t < 8; ++t) VT[dch * 8 + t][rowj] = u.e[t];
        }
        __syncthreads();
        if (j0 > imax) continue;

        floatx4 pc[2];
#pragma unroll
        for (int s = 0; s < 2; ++s) {
            bf16x8 kb0 = *(const bf16x8*)(&Ks[s * 16 + l15][quad * 8]);
            bf16x8 kb1 = *(const bf16x8*)(&Ks[s * 16 + l15][32 + quad * 8]);
            floatx4 p = fzero;
            p = mfma_bf16(qa0, kb0, p);
            p = mfma_bf16(qa1, kb1, p);
            pc[s] = p;
        }
        float lg[2][4];
#pragma unroll
        for (int s = 0; s < 2; ++s) {
            int j = j0 + s * 16 + l15;
#pragma unroll
            for (int r = 0; r < 4; ++r) {
                int i = i0 + quad * 4 + r;
                float ff = FF[((size_t)b * T_ + i) * T_ + j];
                lg[s][r] = (j <= i) ? pc[s][r] * scale - ff : -__builtin_inff();
            }
        }
#pragma unroll
        for (int r = 0; r < 4; ++r) {
            float rm = fmaxf(lg[0][r], lg[1][r]);
#pragma unroll
            for (int d = 1; d < 16; d <<= 1) rm = fmaxf(rm, __shfl_xor(rm, d));
            float mn = fmaxf(m_run[r], rm);
            float alpha = __expf(m_run[r] - mn);
            float p0 = __expf(lg[0][r] - mn);
            float p1 = __expf(lg[1][r] - mn);
            lg[0][r] = p0; lg[1][r] = p1;
            float ps = p0 + p1;
#pragma unroll
            for (int d = 1; d < 16; d <<= 1) ps += __shfl_xor(ps, d);
            l_run[r] = l_run[r] * alpha + ps;
            m_run[r] = mn;
#pragma unroll
            for (int nt = 0; nt < 4; ++nt) O[nt][r] *= alpha;
        }
#pragma unroll
        for (int s = 0; s < 2; ++s)
#pragma unroll
            for (int r = 0; r < 4; ++r)
                Pb[wave][quad * 4 + r][s * 16 + l15] = (bf16_t)lg[s][r];
        asm volatile("s_waitcnt lgkmcnt(0)" ::: "memory");
        bf16x8 pa = *(const bf16x8*)(&Pb[wave][l15][quad * 8]);
#pragma unroll
        for (int nt = 0; nt < 4; ++nt) {
            bf16x8 vb = *(const bf16x8*)(&VT[nt * 16 + l15][quad * 8]);
            O[nt] = mfma_bf16(pa, vb, O[nt]);
        }
    }
#pragma unroll
    for (int r = 0; r < 4; ++r) {
        float inv = 1.f / l_run[r];
        int i = i0 + quad * 4 + r;
#pragma unroll
        for (int nt = 0; nt < 4; ++nt)
            y_b[((size_t)b * T_ + i) * C_ + h * HD_ + nt * 16 + l15] =
                (bf16_t)(O[nt][r] * inv);
    }
}

// ---------------------------------------------------------------------------
// K7: out = y @ w_proj^T + b_proj  (plain bf16, LDS-staged)
// ---------------------------------------------------------------------------
__global__ __launch_bounds__(256) void proj_gemm(
    const bf16_t* __restrict__ y_b, const bf16_t* __restrict__ wp_b,
    const float* __restrict__ bias, float* __restrict__ out)
{
    extern __shared__ char lds[];
    int m0 = blockIdx.x * 128, n0 = blockIdx.y * 128;
    floatx4 acc[4][4];
#pragma unroll
    for (int i = 0; i < 4; ++i)
#pragma unroll
        for (int j = 0; j < 4; ++j) acc[i][j] = (floatx4){0.f, 0.f, 0.f, 0.f};
    gemm_loop<false>((const char*)(y_b + (size_t)m0 * C_), nullptr,
                     (const char*)(wp_b + (size_t)n0 * C_), nullptr, lds, acc);

    int tid = threadIdx.x, lane = tid & 63, wave = tid >> 6;
    int l15 = lane & 15, quad = lane >> 4;
    int wr = wave >> 1, wc = wave & 1;
#pragma unroll
    for (int ni = 0; ni < 4; ++ni) {
        int col = n0 + wc * 64 + ni * 16 + l15;
        float bb = bias[col];
#pragma unroll
        for (int mi = 0; mi < 4; ++mi)
#pragma unroll
            for (int r = 0; r < 4; ++r)
                out[(size_t)(m0 + wr * 64 + mi * 16 + quad * 4 + r) * C_ + col] =
                    acc[mi][ni][r] + bb;
    }
}

// ---------------------------------------------------------------------------
extern "C" void kernel_launch(void* const* d_in, const int* in_sizes, int n_in,
                              void* d_out, int out_size, void* d_ws, size_t ws_size,
                              hipStream_t stream)
{
    const float* x      = (const float*)d_in[0];
    const float* w_attn = (const float*)d_in[1];
    const float* b_attn = (const float*)d_in[2];
    const float* w_proj = (const float*)d_in[3];
    const float* b_proj = (const float*)d_in[4];
    const float* sel_w  = (const float*)d_in[5];
    float* out = (float*)d_out;

    char* ws = (char*)d_ws;
    size_t off = 0;
    auto alloc = [&](size_t bytes) {
        void* p = ws + off;
        off += (bytes + 255) & ~(size_t)255;
        return p;
    };
    const size_t MC2 = (size_t)M_ * C_ * 2;          // 6.29 MB
    // Persistent region
    bf16_t* q_hi   = (bf16_t*)alloc(MC2);
    bf16_t* q_lo   = (bf16_t*)alloc(MC2);
    bf16_t* kw_hi  = (bf16_t*)alloc(MC2);
    bf16_t* kw_lo  = (bf16_t*)alloc(MC2);
    bf16_t* k_b    = (bf16_t*)alloc(MC2);
    bf16_t* v_b    = (bf16_t*)alloc(MC2);
    bf16_t* y_b    = (bf16_t*)alloc(MC2);
    bf16_t* wp_b   = (bf16_t*)alloc((size_t)C_ * C_ * 2);
    float*  segsum = (float*)alloc((size_t)B_ * SEG_ * T_ * 4);
    // Aliased region: phase-1 splits and SF never live simultaneously
    char* shared_base = (char*)alloc((size_t)B_ * T_ * T_ * 4);   // 33.55 MB
    bf16_t* x_hi = (bf16_t*)shared_base;
    bf16_t* x_lo = (bf16_t*)(shared_base + MC2);
    bf16_t* w_hi = (bf16_t*)(shared_base + 2 * MC2);
    bf16_t* w_lo = (bf16_t*)(shared_base + 2 * MC2 + (size_t)N3_ * C_ * 2);
    float*  SF   = (float*)shared_base;

    int nx = M_ * C_, nw = N3_ * C_, np = C_ * C_;
    split_f32<<<dim3((nx + 255) / 256), 256, 0, stream>>>(x, x_hi, x_lo, nx);
    split_f32<<<dim3((nw + 255) / 256), 256, 0, stream>>>(w_attn, w_hi, w_lo, nw);
    conv_f32<<<dim3((np + 255) / 256), 256, 0, stream>>>(w_proj, wp_b, np);

    qkv_gemm<<<dim3(M_ / 128, N3_ / 128), 256, 32768, stream>>>(
        x_hi, x_lo, w_hi, w_lo, b_attn, sel_w,
        q_hi, q_lo, kw_hi, kw_lo, k_b, v_b);
    s_gemm<<<dim3(T_ / 128, T_ / 128, B_), 256, 32768, stream>>>(
        q_hi, q_lo, kw_hi, kw_lo, SF);
    scan_seg_sum<<<dim3(B_ * SEG_ * T_ / 256), 256, 0, stream>>>(SF, segsum);
    scan_seg_excl<<<dim3(B_ * T_ / 256), 256, 0, stream>>>(segsum);
    scan_apply<<<dim3(B_ * SEG_ * T_ / 256), 256, 0, stream>>>(SF, segsum);
    attn_kernel<<<dim3(T_ / 64, H_, B_), 256, 0, stream>>>(q_hi, k_b, v_b, SF, y_b);
    proj_gemm<<<dim3(M_ / 128, C_ / 128), 256, 16384, stream>>>(y_b, wp_b, b_proj, out);
}

// Round 4
// 376.892 us; speedup vs baseline: 2.6617x; 1.1931x over previous
//
#include <hip/hip_runtime.h>

#define B_   2
#define T_   2048
#define C_   768
#define H_   12
#define HD_  64
#define M_   (B_ * T_)    // 4096 rows
#define N3_  (3 * C_)     // 2304
#define KB_  (C_ * 2)     // 1536 bytes per row (bf16)

typedef __bf16 bf16_t;
typedef bf16_t bf16x8 __attribute__((ext_vector_type(8)));
typedef float  floatx4 __attribute__((ext_vector_type(4)));

__device__ inline floatx4 mfma_bf16(bf16x8 a, bf16x8 b, floatx4 c) {
    return __builtin_amdgcn_mfma_f32_16x16x32_bf16(a, b, c, 0, 0, 0);
}

__device__ __forceinline__ void async_copy16(const void* g, void* l) {
    __builtin_amdgcn_global_load_lds(
        (const __attribute__((address_space(1))) void*)g,
        (__attribute__((address_space(3))) void*)l, 16, 0, 0);
}

// ---------------------------------------------------------------------------
// Shared 128x128-tile GEMM mainloop.
// ---------------------------------------------------------------------------
__device__ __forceinline__ void stage8k(const char* tile, char* ldsbase,
                                        int k0b, int wave, int lane) {
#pragma unroll
    for (int i = 0; i < 2; ++i) {
        int p = (wave * 2 + i) * 64 + lane;     // 16B slot index 0..511
        int r = p >> 2, slot = p & 3;
        int g = slot ^ ((r >> 1) & 3);
        async_copy16(tile + (size_t)r * KB_ + k0b + g * 16, ldsbase + p * 16);
    }
}

__device__ __forceinline__ bf16x8 frag_read(const char* ldsbase, int row, int quad) {
    int slot = quad ^ ((row >> 1) & 3);
    return *(const bf16x8*)(ldsbase + row * 64 + slot * 16);
}

template<bool TRIPLE>
__device__ __forceinline__ void gemm_loop(
    const char* Ah, const char* Al, const char* Bh, const char* Bl,
    char* lds, floatx4 (&acc)[4][4])
{
    int tid = threadIdx.x, lane = tid & 63, wave = tid >> 6;
    int l15 = lane & 15, quad = lane >> 4;
    int wr = wave >> 1, wc = wave & 1;
    char* LAh = lds;
    char* LAl = lds + 8192;
    char* LBh = lds + (TRIPLE ? 16384 : 8192);
    char* LBl = lds + 24576;
#pragma unroll 1
    for (int k0 = 0; k0 < KB_; k0 += 64) {       // 32 bf16 per chunk
        __syncthreads();
        stage8k(Ah, LAh, k0, wave, lane);
        if (TRIPLE) stage8k(Al, LAl, k0, wave, lane);
        stage8k(Bh, LBh, k0, wave, lane);
        if (TRIPLE) stage8k(Bl, LBl, k0, wave, lane);
        __syncthreads();
        bf16x8 ah[4], al[4], bh[4], bl[4];
#pragma unroll
        for (int t = 0; t < 4; ++t) {
            ah[t] = frag_read(LAh, wr * 64 + t * 16 + l15, quad);
            bh[t] = frag_read(LBh, wc * 64 + t * 16 + l15, quad);
            if (TRIPLE) {
                al[t] = frag_read(LAl, wr * 64 + t * 16 + l15, quad);
                bl[t] = frag_read(LBl, wc * 64 + t * 16 + l15, quad);
            }
        }
#pragma unroll
        for (int mi = 0; mi < 4; ++mi)
#pragma unroll
            for (int ni = 0; ni < 4; ++ni) {
                acc[mi][ni] = mfma_bf16(ah[mi], bh[ni], acc[mi][ni]);
                if (TRIPLE) {
                    acc[mi][ni] = mfma_bf16(ah[mi], bl[ni], acc[mi][ni]);
                    acc[mi][ni] = mfma_bf16(al[mi], bh[ni], acc[mi][ni]);
                }
            }
    }
}

// ---------------------------------------------------------------------------
// K0: fp32 -> bf16 hi/lo split (and plain convert)
// ---------------------------------------------------------------------------
__global__ __launch_bounds__(256) void split_f32(
    const float* __restrict__ src, bf16_t* __restrict__ hi,
    bf16_t* __restrict__ lo, int n)
{
    int i = blockIdx.x * 256 + threadIdx.x;
    if (i < n) {
        float f = src[i];
        bf16_t h = (bf16_t)f;
        hi[i] = h;
        lo[i] = (bf16_t)(f - (float)h);
    }
}

__global__ __launch_bounds__(256) void conv_f32(
    const float* __restrict__ src, bf16_t* __restrict__ dst, int n)
{
    int i = blockIdx.x * 256 + threadIdx.x;
    if (i < n) dst[i] = (bf16_t)src[i];
}

// ---------------------------------------------------------------------------
// K1: qkv = x @ w_attn^T + b_attn  (bf16x3).
// ---------------------------------------------------------------------------
__global__ __launch_bounds__(256) void qkv_gemm(
    const bf16_t* __restrict__ x_hi, const bf16_t* __restrict__ x_lo,
    const bf16_t* __restrict__ w_hi, const bf16_t* __restrict__ w_lo,
    const float* __restrict__ bias, const float* __restrict__ selw,
    bf16_t* __restrict__ q_hi, bf16_t* __restrict__ q_lo,
    bf16_t* __restrict__ kw_hi, bf16_t* __restrict__ kw_lo,
    bf16_t* __restrict__ k_b, bf16_t* __restrict__ v_b)
{
    extern __shared__ char lds[];
    int m0 = blockIdx.x * 128, n0 = blockIdx.y * 128;
    floatx4 acc[4][4];
#pragma unroll
    for (int i = 0; i < 4; ++i)
#pragma unroll
        for (int j = 0; j < 4; ++j) acc[i][j] = (floatx4){0.f, 0.f, 0.f, 0.f};
    gemm_loop<true>((const char*)(x_hi + (size_t)m0 * C_),
                    (const char*)(x_lo + (size_t)m0 * C_),
                    (const char*)(w_hi + (size_t)n0 * C_),
                    (const char*)(w_lo + (size_t)n0 * C_), lds, acc);

    int tid = threadIdx.x, lane = tid & 63, wave = tid >> 6;
    int l15 = lane & 15, quad = lane >> 4;
    int wr = wave >> 1, wc = wave & 1;
    int cb = n0 + wc * 64;   // wave-uniform: section (q/k/v) is uniform
#pragma unroll
    for (int ni = 0; ni < 4; ++ni) {
        int col = cb + ni * 16 + l15;
        float bb = bias[col];
#pragma unroll
        for (int mi = 0; mi < 4; ++mi)
#pragma unroll
            for (int r = 0; r < 4; ++r) {
                int row = m0 + wr * 64 + mi * 16 + quad * 4 + r;
                float v = acc[mi][ni][r] + bb;
                if (cb < C_) {
                    bf16_t h = (bf16_t)v;
                    q_hi[(size_t)row * C_ + col] = h;
                    q_lo[(size_t)row * C_ + col] = (bf16_t)(v - (float)h);
                } else if (cb < 2 * C_) {
                    int c2 = col - C_;
                    k_b[(size_t)row * C_ + c2] = (bf16_t)v;
                    float kw = v * selw[c2 >> 6];
                    bf16_t h = (bf16_t)kw;
                    kw_hi[(size_t)row * C_ + c2] = h;
                    kw_lo[(size_t)row * C_ + c2] = (bf16_t)(kw - (float)h);
                } else {
                    v_b[(size_t)row * C_ + (col - 2 * C_)] = (bf16_t)v;
                }
            }
    }
}

// ---------------------------------------------------------------------------
// K2: S[b,i,j] = (1<=j<i) ? relu(0.125 * q_i . kw_j) : 0   (bf16x3)
// ---------------------------------------------------------------------------
__global__ __launch_bounds__(256) void s_gemm(
    const bf16_t* __restrict__ q_hi, const bf16_t* __restrict__ q_lo,
    const bf16_t* __restrict__ kw_hi, const bf16_t* __restrict__ kw_lo,
    float* __restrict__ SF)
{
    extern __shared__ char lds[];
    int i0 = blockIdx.x * 128, j0 = blockIdx.y * 128, b = blockIdx.z;
    float* out = SF + (size_t)b * T_ * T_;
    int tid = threadIdx.x;
    if (j0 > i0) {   // fully-masked tile: zero-fill (scan needs init'd buffer)
        float4 z = {0.f, 0.f, 0.f, 0.f};
        float* p = out + (size_t)(i0 + (tid >> 1)) * T_ + j0 + (tid & 1) * 64;
#pragma unroll
        for (int c = 0; c < 16; ++c) ((float4*)p)[c] = z;
        return;
    }
    floatx4 acc[4][4];
#pragma unroll
    for (int i = 0; i < 4; ++i)
#pragma unroll
        for (int j = 0; j < 4; ++j) acc[i][j] = (floatx4){0.f, 0.f, 0.f, 0.f};
    size_t arow = ((size_t)b * T_ + i0) * C_;
    size_t brow = ((size_t)b * T_ + j0) * C_;
    gemm_loop<true>((const char*)(q_hi + arow), (const char*)(q_lo + arow),
                    (const char*)(kw_hi + brow), (const char*)(kw_lo + brow),
                    lds, acc);

    int lane = tid & 63, wave = tid >> 6;
    int l15 = lane & 15, quad = lane >> 4;
    int wr = wave >> 1, wc = wave & 1;
#pragma unroll
    for (int ni = 0; ni < 4; ++ni) {
        int j = j0 + wc * 64 + ni * 16 + l15;
#pragma unroll
        for (int mi = 0; mi < 4; ++mi)
#pragma unroll
            for (int r = 0; r < 4; ++r) {
                int i = i0 + wr * 64 + mi * 16 + quad * 4 + r;
                float s = 0.125f * acc[mi][ni][r];
                s = (j >= 1 && j < i) ? fmaxf(s, 0.f) : 0.f;
                out[(size_t)i * T_ + j] = s;
            }
    }
}

// ---------------------------------------------------------------------------
// K3-K5: per-column exclusive prefix sum over rows (FF_shifted), 3-phase.
// ---------------------------------------------------------------------------
#define SEG_    16
#define SEGLEN_ (T_ / SEG_)  // 128

__global__ __launch_bounds__(256) void scan_seg_sum(
    const float* __restrict__ SF, float* __restrict__ segsum)
{
    int gid  = blockIdx.x * 256 + threadIdx.x;
    int j    = gid & (T_ - 1);
    int rest = gid >> 11;
    int seg  = rest & (SEG_ - 1);
    int b    = rest >> 4;
    const float* col = SF + (size_t)b * T_ * T_ + (size_t)(seg * SEGLEN_) * T_ + j;
    float s = 0.f;
#pragma unroll 8
    for (int i = 0; i < SEGLEN_; ++i) s += col[(size_t)i * T_];
    segsum[((size_t)b * SEG_ + seg) * T_ + j] = s;
}

__global__ __launch_bounds__(256) void scan_seg_excl(float* __restrict__ segsum)
{
    int gid = blockIdx.x * 256 + threadIdx.x;
    int j = gid & (T_ - 1);
    int b = gid >> 11;
    float run = 0.f;
#pragma unroll
    for (int s = 0; s < SEG_; ++s) {
        size_t idx = ((size_t)b * SEG_ + s) * T_ + j;
        float v = segsum[idx];
        segsum[idx] = run;
        run += v;
    }
}

__global__ __launch_bounds__(256) void scan_apply(
    float* __restrict__ SF, const float* __restrict__ segsum)
{
    int gid  = blockIdx.x * 256 + threadIdx.x;
    int j    = gid & (T_ - 1);
    int rest = gid >> 11;
    int seg  = rest & (SEG_ - 1);
    int b    = rest >> 4;
    float run = segsum[((size_t)b * SEG_ + seg) * T_ + j];
    float* col = SF + (size_t)b * T_ * T_ + (size_t)(seg * SEGLEN_) * T_ + j;
#pragma unroll 4
    for (int i = 0; i < SEGLEN_; ++i) {
        float s = col[(size_t)i * T_];
        col[(size_t)i * T_] = run;   // exclusive: FF_shifted[i,j]
        run += s;
    }
}

// ---------------------------------------------------------------------------
// K5b: V -> V^T  (per (b,h): [T][64] -> [64][T]).
// FIX (round 3 bug): each thread now loads 16 elements (two int4), covering
// the full 64x64 tile; previous version loaded only cols 0..31 and left
// cols 32..63 as LDS poison -> upper half of every head's V was garbage.
// ---------------------------------------------------------------------------
__global__ __launch_bounds__(256) void vt_kernel(
    const bf16_t* __restrict__ v_b, bf16_t* __restrict__ vt)
{
    __shared__ bf16_t tile[64][72];
    int t0 = blockIdx.x * 64, h = blockIdx.y, b = blockIdx.z;
    int tid = threadIdx.x;
    int r = tid >> 2, sl = tid & 3;           // r: 0..63, sl: 0..3 (16 elems each)
    const bf16_t* src = v_b + ((size_t)(b * T_ + t0 + r)) * C_ + h * HD_ + sl * 16;
    *(int4*)&tile[r][sl * 16]     = *(const int4*)src;
    *(int4*)&tile[r][sl * 16 + 8] = *(const int4*)(src + 8);
    __syncthreads();
    int hd = tid >> 2, q = tid & 3;
#pragma unroll
    for (int half = 0; half < 2; ++half) {
        int c0 = (q * 2 + half) * 8;
        union { int4 i4; bf16_t e[8]; } u;
#pragma unroll
        for (int kk = 0; kk < 8; ++kk) u.e[kk] = tile[c0 + kk][hd];
        *(int4*)(vt + ((size_t)(b * H_ + h) * HD_ + hd) * T_ + t0 + c0) = u.i4;
    }
}

// ---------------------------------------------------------------------------
// K6: barrier-free flash attention with FF offset.
// Block = (b, h, 16-row i-tile), 4 waves; wave w handles j-tiles t === w mod 4
// (32 cols each) with its own online-softmax state; K and V^T fragments load
// DIRECTLY from global (L2-resident); only LDS use in the loop is the
// wave-private P C->A roundtrip. One barrier total, then a 4-way merge.
// ---------------------------------------------------------------------------
__global__ __launch_bounds__(256) void attn_kernel(
    const bf16_t* __restrict__ q_b, const bf16_t* __restrict__ k_b,
    const bf16_t* __restrict__ vt_g, const float* __restrict__ FF,
    bf16_t* __restrict__ y_b)
{
    __shared__ __align__(16) bf16_t Pb[4][16][40];
    __shared__ float Om[4][16][68];
    __shared__ float Ml[4][16][2];

    int tid = threadIdx.x, lane = tid & 63, wave = tid >> 6;
    int l15 = lane & 15, quad = lane >> 4;
    int itile = blockIdx.x, h = blockIdx.y, b = blockIdx.z;
    int i0 = itile * 16;
    int jlimit = i0 + 16;
    const float scale = 0.125f;
    const floatx4 fzero = {0.f, 0.f, 0.f, 0.f};

    const bf16_t* qrow = q_b + ((size_t)b * T_ + i0 + l15) * C_ + h * HD_;
    bf16x8 qa0 = *(const bf16x8*)(qrow + quad * 8);
    bf16x8 qa1 = *(const bf16x8*)(qrow + 32 + quad * 8);

    const bf16_t* kbase = k_b + (size_t)b * T_ * C_ + h * HD_;
    const bf16_t* vbase = vt_g + (size_t)(b * H_ + h) * HD_ * T_;
    const float*  ffbase = FF + ((size_t)b * T_ + i0) * T_;

    float m_run[4], l_run[4];
    floatx4 O[4];
#pragma unroll
    for (int r = 0; r < 4; ++r) { m_run[r] = -__builtin_inff(); l_run[r] = 0.f; }
#pragma unroll
    for (int nt = 0; nt < 4; ++nt) O[nt] = fzero;

    for (int j0 = wave * 32; j0 < jlimit; j0 += 128) {
        // K fragments direct from global (16 aligned 64B lines per load)
        bf16x8 kb[2][2];
#pragma unroll
        for (int s = 0; s < 2; ++s) {
            const bf16_t* kr = kbase + (size_t)(j0 + s * 16 + l15) * C_;
            kb[s][0] = *(const bf16x8*)(kr + quad * 8);
            kb[s][1] = *(const bf16x8*)(kr + 32 + quad * 8);
        }
        // V^T fragments direct from global
        bf16x8 vb[4];
#pragma unroll
        for (int nt = 0; nt < 4; ++nt)
            vb[nt] = *(const bf16x8*)(vbase + (size_t)(nt * 16 + l15) * T_ + j0 + quad * 8);
        // FF tile
        float ff[2][4];
#pragma unroll
        for (int s = 0; s < 2; ++s)
#pragma unroll
            for (int r = 0; r < 4; ++r)
                ff[s][r] = ffbase[(size_t)(quad * 4 + r) * T_ + j0 + s * 16 + l15];

        // QK^T
        floatx4 pc[2];
#pragma unroll
        for (int s = 0; s < 2; ++s) {
            floatx4 p = fzero;
            p = mfma_bf16(qa0, kb[s][0], p);
            p = mfma_bf16(qa1, kb[s][1], p);
            pc[s] = p;
        }
        // logits
        float lg[2][4];
#pragma unroll
        for (int s = 0; s < 2; ++s) {
            int j = j0 + s * 16 + l15;
#pragma unroll
            for (int r = 0; r < 4; ++r) {
                int i = i0 + quad * 4 + r;
                lg[s][r] = (j <= i) ? pc[s][r] * scale - ff[s][r] : -__builtin_inff();
            }
        }
        // online softmax per row (row = quad*4+r shared by the quad's 16 lanes)
#pragma unroll
        for (int r = 0; r < 4; ++r) {
            float rm = fmaxf(lg[0][r], lg[1][r]);
#pragma unroll
            for (int d = 1; d < 16; d <<= 1) rm = fmaxf(rm, __shfl_xor(rm, d));
            float mn = fmaxf(m_run[r], rm);
            float mnu = fmaxf(mn, -1e30f);   // guard: all-masked tile -> no inf-inf
            float alpha = __expf(m_run[r] - mnu);
            float p0 = __expf(lg[0][r] - mnu);
            float p1 = __expf(lg[1][r] - mnu);
            lg[0][r] = p0; lg[1][r] = p1;
            float ps = p0 + p1;
#pragma unroll
            for (int d = 1; d < 16; d <<= 1) ps += __shfl_xor(ps, d);
            l_run[r] = l_run[r] * alpha + ps;
            m_run[r] = mn;
#pragma unroll
            for (int nt = 0; nt < 4; ++nt) O[nt][r] *= alpha;
        }
        // P: C-layout regs -> wave-private LDS -> A-layout frag
#pragma unroll
        for (int s = 0; s < 2; ++s)
#pragma unroll
            for (int r = 0; r < 4; ++r)
                Pb[wave][quad * 4 + r][s * 16 + l15] = (bf16_t)lg[s][r];
        asm volatile("s_waitcnt lgkmcnt(0)" ::: "memory");
        bf16x8 pa = *(const bf16x8*)(&Pb[wave][l15][quad * 8]);
#pragma unroll
        for (int nt = 0; nt < 4; ++nt)
            O[nt] = mfma_bf16(pa, vb[nt], O[nt]);
    }

    // publish per-wave partial state
#pragma unroll
    for (int r = 0; r < 4; ++r) {
        Ml[wave][quad * 4 + r][0] = m_run[r];
        Ml[wave][quad * 4 + r][1] = l_run[r];
#pragma unroll
        for (int nt = 0; nt < 4; ++nt)
            Om[wave][quad * 4 + r][nt * 16 + l15] = O[nt][r];
    }
    __syncthreads();

    // 4-way merge: thread -> (row, 4-col group)
    int row = tid >> 4, cg = tid & 15;
    float mstar = Ml[0][row][0];
#pragma unroll
    for (int w = 1; w < 4; ++w) mstar = fmaxf(mstar, Ml[w][row][0]);
    float aw[4], lsum = 0.f;
#pragma unroll
    for (int w = 0; w < 4; ++w) {
        aw[w] = __expf(Ml[w][row][0] - mstar);
        lsum += aw[w] * Ml[w][row][1];
    }
    float inv = 1.f / lsum;
    union { uint2 u2; bf16_t e[4]; } pk;
#pragma unroll
    for (int c = 0; c < 4; ++c) {
        float o = 0.f;
#pragma unroll
        for (int w = 0; w < 4; ++w) o += aw[w] * Om[w][row][cg * 4 + c];
        pk.e[c] = (bf16_t)(o * inv);
    }
    *(uint2*)(y_b + ((size_t)b * T_ + i0 + row) * C_ + h * HD_ + cg * 4) = pk.u2;
}

// ---------------------------------------------------------------------------
// K7: out = y @ w_proj^T + b_proj  (plain bf16, LDS-staged)
// ---------------------------------------------------------------------------
__global__ __launch_bounds__(256) void proj_gemm(
    const bf16_t* __restrict__ y_b, const bf16_t* __restrict__ wp_b,
    const float* __restrict__ bias, float* __restrict__ out)
{
    extern __shared__ char lds[];
    int m0 = blockIdx.x * 128, n0 = blockIdx.y * 128;
    floatx4 acc[4][4];
#pragma unroll
    for (int i = 0; i < 4; ++i)
#pragma unroll
        for (int j = 0; j < 4; ++j) acc[i][j] = (floatx4){0.f, 0.f, 0.f, 0.f};
    gemm_loop<false>((const char*)(y_b + (size_t)m0 * C_), nullptr,
                     (const char*)(wp_b + (size_t)n0 * C_), nullptr, lds, acc);

    int tid = threadIdx.x, lane = tid & 63, wave = tid >> 6;
    int l15 = lane & 15, quad = lane >> 4;
    int wr = wave >> 1, wc = wave & 1;
#pragma unroll
    for (int ni = 0; ni < 4; ++ni) {
        int col = n0 + wc * 64 + ni * 16 + l15;
        float bb = bias[col];
#pragma unroll
        for (int mi = 0; mi < 4; ++mi)
#pragma unroll
            for (int r = 0; r < 4; ++r)
                out[(size_t)(m0 + wr * 64 + mi * 16 + quad * 4 + r) * C_ + col] =
                    acc[mi][ni][r] + bb;
    }
}

// ---------------------------------------------------------------------------
extern "C" void kernel_launch(void* const* d_in, const int* in_sizes, int n_in,
                              void* d_out, int out_size, void* d_ws, size_t ws_size,
                              hipStream_t stream)
{
    const float* x      = (const float*)d_in[0];
    const float* w_attn = (const float*)d_in[1];
    const float* b_attn = (const float*)d_in[2];
    const float* w_proj = (const float*)d_in[3];
    const float* b_proj = (const float*)d_in[4];
    const float* sel_w  = (const float*)d_in[5];
    float* out = (float*)d_out;

    char* ws = (char*)d_ws;
    size_t off = 0;
    auto alloc = [&](size_t bytes) {
        void* p = ws + off;
        off += (bytes + 255) & ~(size_t)255;
        return p;
    };
    const size_t MC2 = (size_t)M_ * C_ * 2;          // 6.29 MB
    // Persistent region
    bf16_t* q_hi   = (bf16_t*)alloc(MC2);
    bf16_t* q_lo   = (bf16_t*)alloc(MC2);
    bf16_t* kw_hi  = (bf16_t*)alloc(MC2);   // dead after s_gemm -> reused as vt
    bf16_t* kw_lo  = (bf16_t*)alloc(MC2);
    bf16_t* k_b    = (bf16_t*)alloc(MC2);
    bf16_t* v_b    = (bf16_t*)alloc(MC2);
    bf16_t* y_b    = (bf16_t*)alloc(MC2);
    bf16_t* wp_b   = (bf16_t*)alloc((size_t)C_ * C_ * 2);
    float*  segsum = (float*)alloc((size_t)B_ * SEG_ * T_ * 4);
    // Aliased region: phase-1 splits and SF never live simultaneously
    char* shared_base = (char*)alloc((size_t)B_ * T_ * T_ * 4);   // 33.55 MB
    bf16_t* x_hi = (bf16_t*)shared_base;
    bf16_t* x_lo = (bf16_t*)(shared_base + MC2);
    bf16_t* w_hi = (bf16_t*)(shared_base + 2 * MC2);
    bf16_t* w_lo = (bf16_t*)(shared_base + 2 * MC2 + (size_t)N3_ * C_ * 2);
    float*  SF   = (float*)shared_base;
    bf16_t* vt   = kw_hi;   // alias: vt_kernel runs after s_gemm's last read

    int nx = M_ * C_, nw = N3_ * C_, np = C_ * C_;
    split_f32<<<dim3((nx + 255) / 256), 256, 0, stream>>>(x, x_hi, x_lo, nx);
    split_f32<<<dim3((nw + 255) / 256), 256, 0, stream>>>(w_attn, w_hi, w_lo, nw);
    conv_f32<<<dim3((np + 255) / 256), 256, 0, stream>>>(w_proj, wp_b, np);

    qkv_gemm<<<dim3(M_ / 128, N3_ / 128), 256, 32768, stream>>>(
        x_hi, x_lo, w_hi, w_lo, b_attn, sel_w,
        q_hi, q_lo, kw_hi, kw_lo, k_b, v_b);
    s_gemm<<<dim3(T_ / 128, T_ / 128, B_), 256, 32768, stream>>>(
        q_hi, q_lo, kw_hi, kw_lo, SF);
    vt_kernel<<<dim3(T_ / 64, H_, B_), 256, 0, stream>>>(v_b, vt);
    scan_seg_sum<<<dim3(B_ * SEG_ * T_ / 256), 256, 0, stream>>>(SF, segsum);
    scan_seg_excl<<<dim3(B_ * T_ / 256), 256, 0, stream>>>(segsum);
    scan_apply<<<dim3(B_ * SEG_ * T_ / 256), 256, 0, stream>>>(SF, segsum);
    attn_kernel<<<dim3(T_ / 16, H_, B_), 256, 0, stream>>>(q_hi, k_b, vt, SF, y_b);
    proj_gemm<<<dim3(M_ / 128, C_ / 128), 256, 16384, stream>>>(y_b, wp_b, b_proj, out);
}